// Round 6
// baseline (197.923 us; speedup 1.0000x reference)
//
#include <hip/hip_runtime.h>
#include <hip/hip_bf16.h>
#include <math.h>

#define NW 4096
#define NL 32
#define ND 256
#define ND2 512

typedef __attribute__((ext_vector_type(8))) short short8;
typedef __attribute__((ext_vector_type(4))) float floatx4;

__device__ inline float bitsf(unsigned u) {
  union { unsigned u; float f; } v;
  v.u = u;
  return v.f;
}

// ---------------------------------------------------------------------------
// ws layout:
//   ctr   int[8]    ctrA (prep->table spin), ctrB (fc12 last-block)
//   wT    fp32 [3][256][256]                 (chr conv w, [k][ci][co])
//   part  fp32 [512][64]
//   h     fp32 [1024]
//   Tb    bf16 [4 cotile][3 k][128 c][64 co] (char conv tables)
//   u     bf16 [4098][512]  (guard rows at both ends)
//   Wb    bf16 [3][512 co][512 ci]           (sent conv w)
//
// R5 bug fixed: sent-w needs 3072 blocks (786432 elems / 256); R5's grid
// gave it 1536, leaving half of Wb poisoned. Grid is now 3937:
//   [0,768) chr-w -> wT, [768,864) table (spin), [864,3936) sent-w, 3936 guard.
// ---------------------------------------------------------------------------

// K1: prep + table fused via spin-wait (release/acquire pattern validated
// bit-exact in R1/R4). Writers first in grid; 864 < residency cap -> no
// deadlock.
__global__ __launch_bounds__(256) void prep_table_kernel(
    const float* __restrict__ conv_sent_w, const float* __restrict__ conv_chr_w,
    const float* __restrict__ chr_emb, float* __restrict__ wT,
    __hip_bfloat16* __restrict__ Wb, __hip_bfloat16* __restrict__ Tb,
    short* __restrict__ u_base, int* __restrict__ ctrA) {
  __shared__ float s_e[4][256];
  const int b = blockIdx.x;
  const int tid = threadIdx.x;
  if (b < 768) {                          // chr w: 196608 elems, coalesced read
    int idx = b * 256 + tid;
    float v = conv_chr_w[idx];
    int co = idx / 768;
    int rem = idx - co * 768;
    int ci = rem / 3;
    int k = rem - ci * 3;
    wT[k * 65536 + ci * 256 + co] = v;
    __syncthreads();                      // drains stores (vmcnt before barrier)
    if (tid == 0)
      __hip_atomic_fetch_add(ctrA, 1, __ATOMIC_RELEASE, __HIP_MEMORY_SCOPE_AGENT);
    return;
  }
  if (b < 864) {                          // table job, R0-verbatim body
    if (tid == 0) {
      while (__hip_atomic_load(ctrA, __ATOMIC_RELAXED, __HIP_MEMORY_SCOPE_AGENT) < 768)
        __builtin_amdgcn_s_sleep(2);
    }
    __syncthreads();
    __builtin_amdgcn_fence(__ATOMIC_ACQUIRE, "agent");
    const int tb = b - 768;
    const int k = tb >> 5;
    const int c0 = (tb & 31) * 4;
    const int co = tid;
#pragma unroll
    for (int j = 0; j < 4; ++j) s_e[j][co] = chr_emb[(c0 + j) * 256 + co];
    __syncthreads();
    const float* wk = wT + k * 65536;
    float a0 = 0.f, a1 = 0.f, a2 = 0.f, a3 = 0.f;
#pragma unroll 8
    for (int ci = 0; ci < 256; ++ci) {
      float w = wk[ci * 256 + co];
      a0 = fmaf(s_e[0][ci], w, a0);
      a1 = fmaf(s_e[1][ci], w, a1);
      a2 = fmaf(s_e[2][ci], w, a2);
      a3 = fmaf(s_e[3][ci], w, a3);
    }
    int base = ((co >> 6) * 3 + k) * 8192 + (co & 63);
    Tb[base + (c0 + 0) * 64] = __float2bfloat16(a0);
    Tb[base + (c0 + 1) * 64] = __float2bfloat16(a1);
    Tb[base + (c0 + 2) * 64] = __float2bfloat16(a2);
    Tb[base + (c0 + 3) * 64] = __float2bfloat16(a3);
    return;
  }
  if (b < 3936) {                         // sent w: 786432 elems, 3072 blocks
    int idx = (b - 864) * 256 + tid;
    float v = conv_sent_w[idx];
    int co = idx / 1536;
    int rem = idx - co * 1536;
    int ci = rem / 3;
    int k = rem - ci * 3;
    Wb[k * 262144 + co * 512 + ci] = __float2bfloat16(v);
    return;
  }
  // guard rows (t=-1, t=4096)
  u_base[tid] = 0;
  u_base[tid + 256] = 0;
  u_base[4097 * 512 + tid] = 0;
  u_base[4097 * 512 + tid + 256] = 0;
}

// K2: char conv + word-emb gather. 512 blocks (ct = b>>7, 32-word chunk),
// 2 blocks/CU (52.4 KB LDS). Unchanged (R4-proven).
__global__ __launch_bounds__(256) void char_word_kernel(
    const int* __restrict__ words, const int* __restrict__ wic,
    const __hip_bfloat16* __restrict__ Tb, const float* __restrict__ word_emb,
    const float* __restrict__ bias, __hip_bfloat16* __restrict__ u0) {
  __shared__ short sT[3 * 128 * 64];   // 48 KB
  __shared__ int s_wic[32 * 32];       // 4 KB
  __shared__ int s_wid[32];
  const int ct = blockIdx.x >> 7;
  const int w0 = (blockIdx.x & 127) * 32;
  const int tid = threadIdx.x;
  {
    const uint4* src = (const uint4*)((const short*)Tb + ct * 24576);
    uint4* dst = (uint4*)sT;
#pragma unroll
    for (int i = 0; i < 12; ++i) dst[tid + i * 256] = src[tid + i * 256];
    ((int4*)s_wic)[tid] = ((const int4*)(wic + w0 * 32))[tid];
    if (tid < 32) s_wid[tid] = words[w0 + tid];
  }
  __syncthreads();
  {
    const int co_l = tid & 63, slot = tid >> 6;
#pragma unroll
    for (int wi = 0; wi < 8; ++wi) {
      int wl = slot * 8 + wi;
      u0[(w0 + wl) * ND2 + ct * 64 + co_l] =
          __float2bfloat16(word_emb[s_wid[wl] * ND + ct * 64 + co_l]);
    }
  }
  const int wave = tid >> 6, lane = tid & 63;
  const int half = lane >> 5, co2 = (lane & 31) * 2;
  const float2 bb = *(const float2*)&bias[ct * 64 + co2];
  const short* T0p = sT;
  const short* T1p = sT + 8192;
  const short* T2p = sT + 16384;
#pragma unroll
  for (int p = 0; p < 4; ++p) {
    const int wl = wave * 8 + p * 2 + half;
    int chv[32];
    const int4* c4 = (const int4*)(s_wic + wl * 32);
#pragma unroll
    for (int j = 0; j < 8; ++j) {
      int4 cc = c4[j];
      chv[4 * j + 0] = cc.x; chv[4 * j + 1] = cc.y;
      chv[4 * j + 2] = cc.z; chv[4 * j + 3] = cc.w;
    }
    float m0 = -INFINITY, m1 = -INFINITY;
#pragma unroll
    for (int t = 0; t < NL; ++t) {
      unsigned v1 = *(const unsigned*)&T1p[chv[t] * 64 + co2];
      float s0 = bitsf(v1 << 16);
      float s1 = bitsf(v1 & 0xffff0000u);
      if (t > 0) {
        unsigned v0 = *(const unsigned*)&T0p[chv[t - 1] * 64 + co2];
        s0 += bitsf(v0 << 16);
        s1 += bitsf(v0 & 0xffff0000u);
      }
      if (t < NL - 1) {
        unsigned v2 = *(const unsigned*)&T2p[chv[t + 1] * 64 + co2];
        s0 += bitsf(v2 << 16);
        s1 += bitsf(v2 & 0xffff0000u);
      }
      m0 = fmaxf(m0, s0);
      m1 = fmaxf(m1, s1);
    }
    __hip_bfloat162 hh;
    hh.x = __float2bfloat16(m0 + bb.x);
    hh.y = __float2bfloat16(m1 + bb.y);
    *(__hip_bfloat162*)&u0[(w0 + wl) * ND2 + ND + ct * 64 + co2] = hh;
  }
}

// K3: sentence conv GEMM. 512 blocks, 2/CU. Double-buffered LDS, one barrier
// per K-step, distance-1 register prefetch. Same swizzle (0 conflicts), same
// MFMA order as R0/R4 -> bit-exact.
__global__ __launch_bounds__(256, 2) void sent_conv_mfma(
    const __hip_bfloat16* __restrict__ u0,
    const __hip_bfloat16* __restrict__ Wb,
    float* __restrict__ partial) {
  __shared__ short As[2][64 * 64];   // 16 KB
  __shared__ short Bs[2][64 * 64];   // 16 KB
  __shared__ float sm[4][32];
  const int tid = threadIdx.x;
  const int t0 = blockIdx.x * 64;
  const int co0 = blockIdx.y * 64;
  const int wave = tid >> 6, lane = tid & 63;
  const int wy = wave >> 1, wx = wave & 1;
  const int m = lane & 15, q = lane >> 4;

  floatx4 acc[2][2];
#pragma unroll
  for (int i = 0; i < 2; ++i)
#pragma unroll
    for (int j = 0; j < 2; ++j) acc[i][j] = (floatx4){0.f, 0.f, 0.f, 0.f};

  int aoff[2][2], boff[2][2];
#pragma unroll
  for (int kk = 0; kk < 2; ++kk) {
#pragma unroll
    for (int i = 0; i < 2; ++i) {
      int row = wy * 32 + i * 16 + m;
      aoff[kk][i] = row * 64 + (((kk * 4 + q) ^ (row & 7)) * 8);
      row = wx * 32 + i * 16 + m;
      boff[kk][i] = row * 64 + (((kk * 4 + q) ^ (row & 7)) * 8);
    }
  }

  const int sc = tid & 7, sr = tid >> 3;
  const int swc = (sc ^ (sr & 7)) * 8;
  const short* WbS = (const short*)Wb;
  const short* uS = (const short*)u0;

  uint4 ra0, ra1, rb0, rb1;
  auto LOADS = [&](int s2) {
    int k = s2 >> 3, ci0 = (s2 & 7) << 6;
    const short* WbK = WbS + k * 262144 + (co0 + sr) * 512 + ci0 + sc * 8;
    const short* uK = uS + (t0 + sr + k - 1) * 512 + ci0 + sc * 8;
    ra0 = *(const uint4*)(WbK);
    ra1 = *(const uint4*)(WbK + 32 * 512);
    rb0 = *(const uint4*)(uK);
    rb1 = *(const uint4*)(uK + 32 * 512);
  };
  auto WRITE = [&](int buf) {
    *(uint4*)&As[buf][sr * 64 + swc] = ra0;
    *(uint4*)&As[buf][(sr + 32) * 64 + swc] = ra1;
    *(uint4*)&Bs[buf][sr * 64 + swc] = rb0;
    *(uint4*)&Bs[buf][(sr + 32) * 64 + swc] = rb1;
  };
  auto MFMA = [&](int buf) {
#pragma unroll
    for (int kk = 0; kk < 2; ++kk) {
      short8 av0 = *(const short8*)&As[buf][aoff[kk][0]];
      short8 av1 = *(const short8*)&As[buf][aoff[kk][1]];
      short8 bv0 = *(const short8*)&Bs[buf][boff[kk][0]];
      short8 bv1 = *(const short8*)&Bs[buf][boff[kk][1]];
      acc[0][0] = __builtin_amdgcn_mfma_f32_16x16x32_bf16(av0, bv0, acc[0][0], 0, 0, 0);
      acc[0][1] = __builtin_amdgcn_mfma_f32_16x16x32_bf16(av0, bv1, acc[0][1], 0, 0, 0);
      acc[1][0] = __builtin_amdgcn_mfma_f32_16x16x32_bf16(av1, bv0, acc[1][0], 0, 0, 0);
      acc[1][1] = __builtin_amdgcn_mfma_f32_16x16x32_bf16(av1, bv1, acc[1][1], 0, 0, 0);
    }
  };

  LOADS(0);
  WRITE(0);
  __syncthreads();
  for (int s = 0; s < 23; ++s) {
    LOADS(s + 1);              // prefetch next step (latency under MFMAs)
    MFMA(s & 1);
    WRITE((s + 1) & 1);        // other buffer: last read was at step s-1
    __syncthreads();           // ONE barrier per step
  }
  MFMA(23 & 1);

#pragma unroll
  for (int i = 0; i < 2; ++i)
#pragma unroll
    for (int r = 0; r < 4; ++r) {
      float x = fmaxf(acc[i][0][r], acc[i][1][r]);
#pragma unroll
      for (int off = 1; off < 16; off <<= 1)
        x = fmaxf(x, __shfl_xor(x, off, 64));
      if (m == 0) sm[wave][i * 16 + q * 4 + r] = x;
    }
  __syncthreads();
  if (tid < 64) {
    int whalf = tid >> 5;
    float v = fmaxf(sm[whalf * 2 + 0][tid & 31], sm[whalf * 2 + 1][tid & 31]);
    partial[(co0 + tid) * 64 + blockIdx.x] = v;
  }
}

// K4: fc1 + fc2 fused (R4-verbatim). grid 128 x 512 threads.
__global__ __launch_bounds__(512) void fc12_kernel(
    const float* __restrict__ partial, const float* __restrict__ bs,
    const float* __restrict__ w1, const float* __restrict__ b1,
    const float* __restrict__ w2, const float* __restrict__ b2,
    float* __restrict__ h, int* __restrict__ ctr, float* __restrict__ out) {
  __shared__ float s_r[512];
  __shared__ int s_last;
  int tid = threadIdx.x;
  {
    const float4* p = (const float4*)(partial + tid * 64);
    float mm = -INFINITY;
#pragma unroll
    for (int j = 0; j < 16; ++j) {
      float4 v = p[j];
      mm = fmaxf(mm, fmaxf(fmaxf(v.x, v.y), fmaxf(v.z, v.w)));
    }
    s_r[tid] = mm + bs[tid];
  }
  __syncthreads();
  int wave = tid >> 6, lane = tid & 63;
  int o = blockIdx.x * 8 + wave;
  const float4* wv = (const float4*)(w1 + o * 512 + lane * 8);
  const float4* rv = (const float4*)(s_r + lane * 8);
  float4 w0 = wv[0], w1v = wv[1];
  float4 r0 = rv[0], r1 = rv[1];
  float acc = w0.x * r0.x + w0.y * r0.y + w0.z * r0.z + w0.w * r0.w +
              w1v.x * r1.x + w1v.y * r1.y + w1v.z * r1.z + w1v.w * r1.w;
#pragma unroll
  for (int off = 32; off >= 1; off >>= 1) acc += __shfl_down(acc, off, 64);
  if (lane == 0) h[o] = tanhf(acc + b1[o]);
  __syncthreads();
  if (tid == 0) {
    int old = __hip_atomic_fetch_add(ctr, 1, __ATOMIC_RELEASE,
                                     __HIP_MEMORY_SCOPE_AGENT);
    s_last = (old == 127) ? 1 : 0;
  }
  __syncthreads();
  if (s_last) {
    __builtin_amdgcn_fence(__ATOMIC_ACQUIRE, "agent");
    if (tid < 128) {
      int o2 = tid >> 6;
      int lane2 = tid & 63;
      float acc2 = 0.f;
#pragma unroll
      for (int j = 0; j < 16; ++j)
        acc2 = fmaf(w2[o2 * 1024 + lane2 + j * 64], h[lane2 + j * 64], acc2);
#pragma unroll
      for (int off = 32; off >= 1; off >>= 1) acc2 += __shfl_down(acc2, off, 64);
      if (lane2 == 0) out[o2] = acc2 + b2[o2];
    }
  }
}

extern "C" void kernel_launch(void* const* d_in, const int* in_sizes, int n_in,
                              void* d_out, int out_size, void* d_ws, size_t ws_size,
                              hipStream_t stream) {
  const int*   words       = (const int*)d_in[0];
  const int*   wic         = (const int*)d_in[1];
  const float* word_emb    = (const float*)d_in[2];
  const float* chr_emb     = (const float*)d_in[3];
  const float* conv_chr_w  = (const float*)d_in[4];
  const float* conv_chr_b  = (const float*)d_in[5];
  const float* conv_sent_w = (const float*)d_in[6];
  const float* conv_sent_b = (const float*)d_in[7];
  const float* w1          = (const float*)d_in[8];
  const float* b1          = (const float*)d_in[9];
  const float* w2          = (const float*)d_in[10];
  const float* b2          = (const float*)d_in[11];
  float* out = (float*)d_out;

  float* ws    = (float*)d_ws;
  int*   ctr   = (int*)ws;                  // 8 ints: ctrA=ctr, ctrB=ctr+4
  float* wT    = ws + 8;                    // 196608 f
  float* part  = wT + 196608;               // 32768 f
  float* h_buf = part + 32768;              // 1024 f
  short* Tb    = (short*)(h_buf + 1024);    // 98304 bf16
  short* u_base = Tb + 98304;               // 4098*512 bf16
  __hip_bfloat16* u0 = (__hip_bfloat16*)(u_base + 512);
  __hip_bfloat16* Wb = (__hip_bfloat16*)(u_base + 4098 * 512);

  hipMemsetAsync(ctr, 0, 32, stream);
  prep_table_kernel<<<3937, 256, 0, stream>>>(conv_sent_w, conv_chr_w, chr_emb,
                                              wT, Wb, (__hip_bfloat16*)Tb,
                                              u_base, ctr);
  char_word_kernel<<<512, 256, 0, stream>>>(words, wic, (const __hip_bfloat16*)Tb,
                                            word_emb, conv_chr_b, u0);
  sent_conv_mfma<<<dim3(64, 8), 256, 0, stream>>>(u0, Wb, part);
  fc12_kernel<<<128, 512, 0, stream>>>(part, conv_sent_b, w1, b1, w2, b2,
                                       h_buf, ctr + 4, out);
}

// Round 7
// 155.192 us; speedup vs baseline: 1.2753x; 1.2753x over previous
//
#include <hip/hip_runtime.h>
#include <hip/hip_bf16.h>
#include <math.h>

#define NW 4096
#define NL 32
#define ND 256
#define ND2 512

typedef __attribute__((ext_vector_type(8))) short short8;
typedef __attribute__((ext_vector_type(4))) float floatx4;

__device__ inline float bitsf(unsigned u) {
  union { unsigned u; float f; } v;
  v.u = u;
  return v.f;
}

// ---------------------------------------------------------------------------
// ws layout:
//   wT    fp32 [3][256][256]                 (chr conv w, [k][ci][co])
//   part  fp32 [512][64]
//   h     fp32 [1024]
//   ctr   int  [4]                            (fc12 last-block counter)
//   Tb    bf16 [4 cotile][3 k][128 c][64 co] (char conv tables)
//   u     bf16 [4098][512]  (guard rows at both ends)
//   Wb    bf16 [3][512 co][512 ci]           (sent conv w)
//
// R6 lesson: per-block agent-scope release/acquire costs an L2
// writeback/invalidate each (multi-XCD coherence point = L3); 768 of them
// added ~40us. Spin fusion reverted to the R4 separate prep+table pair.
// fc12's single last-block release/acquire (count=1) stays — proven cheap.
// ---------------------------------------------------------------------------

// K1: prep. 3841 blocks.
//   b in [0,3072):  sent-w -> Wb, OUTPUT-indexed (coalesced bf16 stores,
//                   stride-12B gather reads absorbed by L1). Same permutation
//                   and values as R4 -> bit-exact.
//   b in [3072,3840): chr-w -> wT (R4-verbatim input-indexed, coalesced reads)
//   b == 3840:      u guard rows + ctr zero
__global__ __launch_bounds__(256) void prep_kernel(
    const float* __restrict__ conv_sent_w, const float* __restrict__ conv_chr_w,
    float* __restrict__ wT, __hip_bfloat16* __restrict__ Wb,
    short* __restrict__ u_base, int* __restrict__ ctr) {
  int b = blockIdx.x;
  int tid = threadIdx.x;
  if (b < 3072) {                         // Wb: 786432 elems, output-indexed
    int idx = b * 256 + tid;              // idx = k*262144 + co*512 + ci
    int k = idx >> 18;
    int rem = idx & 262143;
    int co = rem >> 9;
    int ci = rem & 511;
    Wb[idx] = __float2bfloat16(conv_sent_w[co * 1536 + ci * 3 + k]);
  } else if (b < 3840) {                  // chr w: 196608 elems
    int idx = (b - 3072) * 256 + tid;
    float v = conv_chr_w[idx];
    int co = idx / 768;
    int rem = idx - co * 768;
    int ci = rem / 3;
    int k = rem - ci * 3;
    wT[k * 65536 + ci * 256 + co] = v;
  } else {                                // guard rows (t=-1, t=4096) + ctr
    u_base[tid] = 0;
    u_base[tid + 256] = 0;
    u_base[4097 * 512 + tid] = 0;
    u_base[4097 * 512 + tid + 256] = 0;
    if (tid == 0) ctr[0] = 0;
  }
}

// K2: T tables in bf16, layout [cotile][k][c][64co]
// grid 96: k = b>>5, c0 = (b&31)*4 ; 256 threads = co  (R0/R4 proven)
__global__ __launch_bounds__(256) void table_kernel(
    const float* __restrict__ chr_emb, const float* __restrict__ wT,
    __hip_bfloat16* __restrict__ Tb) {
  __shared__ float s_e[4][256];
  int k = blockIdx.x >> 5;
  int c0 = (blockIdx.x & 31) * 4;
  int co = threadIdx.x;
#pragma unroll
  for (int j = 0; j < 4; ++j) s_e[j][co] = chr_emb[(c0 + j) * 256 + co];
  __syncthreads();
  const float* wk = wT + k * 65536;
  float a0 = 0.f, a1 = 0.f, a2 = 0.f, a3 = 0.f;
#pragma unroll 8
  for (int ci = 0; ci < 256; ++ci) {
    float w = wk[ci * 256 + co];
    a0 = fmaf(s_e[0][ci], w, a0);
    a1 = fmaf(s_e[1][ci], w, a1);
    a2 = fmaf(s_e[2][ci], w, a2);
    a3 = fmaf(s_e[3][ci], w, a3);
  }
  int base = ((co >> 6) * 3 + k) * 8192 + (co & 63);
  Tb[base + (c0 + 0) * 64] = __float2bfloat16(a0);
  Tb[base + (c0 + 1) * 64] = __float2bfloat16(a1);
  Tb[base + (c0 + 2) * 64] = __float2bfloat16(a2);
  Tb[base + (c0 + 3) * 64] = __float2bfloat16(a3);
}

// K3: char conv + word-emb gather. 512 blocks (ct = b>>7, 32-word chunk),
// 2 blocks/CU (52.4 KB LDS). Unchanged (R4-proven).
__global__ __launch_bounds__(256) void char_word_kernel(
    const int* __restrict__ words, const int* __restrict__ wic,
    const __hip_bfloat16* __restrict__ Tb, const float* __restrict__ word_emb,
    const float* __restrict__ bias, __hip_bfloat16* __restrict__ u0) {
  __shared__ short sT[3 * 128 * 64];   // 48 KB
  __shared__ int s_wic[32 * 32];       // 4 KB
  __shared__ int s_wid[32];
  const int ct = blockIdx.x >> 7;
  const int w0 = (blockIdx.x & 127) * 32;
  const int tid = threadIdx.x;
  {
    const uint4* src = (const uint4*)((const short*)Tb + ct * 24576);
    uint4* dst = (uint4*)sT;
#pragma unroll
    for (int i = 0; i < 12; ++i) dst[tid + i * 256] = src[tid + i * 256];
    ((int4*)s_wic)[tid] = ((const int4*)(wic + w0 * 32))[tid];
    if (tid < 32) s_wid[tid] = words[w0 + tid];
  }
  __syncthreads();
  {
    const int co_l = tid & 63, slot = tid >> 6;
#pragma unroll
    for (int wi = 0; wi < 8; ++wi) {
      int wl = slot * 8 + wi;
      u0[(w0 + wl) * ND2 + ct * 64 + co_l] =
          __float2bfloat16(word_emb[s_wid[wl] * ND + ct * 64 + co_l]);
    }
  }
  const int wave = tid >> 6, lane = tid & 63;
  const int half = lane >> 5, co2 = (lane & 31) * 2;
  const float2 bb = *(const float2*)&bias[ct * 64 + co2];
  const short* T0p = sT;
  const short* T1p = sT + 8192;
  const short* T2p = sT + 16384;
#pragma unroll
  for (int p = 0; p < 4; ++p) {
    const int wl = wave * 8 + p * 2 + half;
    int chv[32];
    const int4* c4 = (const int4*)(s_wic + wl * 32);
#pragma unroll
    for (int j = 0; j < 8; ++j) {
      int4 cc = c4[j];
      chv[4 * j + 0] = cc.x; chv[4 * j + 1] = cc.y;
      chv[4 * j + 2] = cc.z; chv[4 * j + 3] = cc.w;
    }
    float m0 = -INFINITY, m1 = -INFINITY;
#pragma unroll
    for (int t = 0; t < NL; ++t) {
      unsigned v1 = *(const unsigned*)&T1p[chv[t] * 64 + co2];
      float s0 = bitsf(v1 << 16);
      float s1 = bitsf(v1 & 0xffff0000u);
      if (t > 0) {
        unsigned v0 = *(const unsigned*)&T0p[chv[t - 1] * 64 + co2];
        s0 += bitsf(v0 << 16);
        s1 += bitsf(v0 & 0xffff0000u);
      }
      if (t < NL - 1) {
        unsigned v2 = *(const unsigned*)&T2p[chv[t + 1] * 64 + co2];
        s0 += bitsf(v2 << 16);
        s1 += bitsf(v2 & 0xffff0000u);
      }
      m0 = fmaxf(m0, s0);
      m1 = fmaxf(m1, s1);
    }
    __hip_bfloat162 hh;
    hh.x = __float2bfloat16(m0 + bb.x);
    hh.y = __float2bfloat16(m1 + bb.y);
    *(__hip_bfloat162*)&u0[(w0 + wl) * ND2 + ND + ct * 64 + co2] = hh;
  }
}

// K4: sentence conv GEMM. 512 blocks, 2/CU. Double-buffered LDS, one barrier
// per K-step, distance-1 register prefetch (R6-verified bit-exact).
__global__ __launch_bounds__(256, 2) void sent_conv_mfma(
    const __hip_bfloat16* __restrict__ u0,
    const __hip_bfloat16* __restrict__ Wb,
    float* __restrict__ partial) {
  __shared__ short As[2][64 * 64];   // 16 KB
  __shared__ short Bs[2][64 * 64];   // 16 KB
  __shared__ float sm[4][32];
  const int tid = threadIdx.x;
  const int t0 = blockIdx.x * 64;
  const int co0 = blockIdx.y * 64;
  const int wave = tid >> 6, lane = tid & 63;
  const int wy = wave >> 1, wx = wave & 1;
  const int m = lane & 15, q = lane >> 4;

  floatx4 acc[2][2];
#pragma unroll
  for (int i = 0; i < 2; ++i)
#pragma unroll
    for (int j = 0; j < 2; ++j) acc[i][j] = (floatx4){0.f, 0.f, 0.f, 0.f};

  int aoff[2][2], boff[2][2];
#pragma unroll
  for (int kk = 0; kk < 2; ++kk) {
#pragma unroll
    for (int i = 0; i < 2; ++i) {
      int row = wy * 32 + i * 16 + m;
      aoff[kk][i] = row * 64 + (((kk * 4 + q) ^ (row & 7)) * 8);
      row = wx * 32 + i * 16 + m;
      boff[kk][i] = row * 64 + (((kk * 4 + q) ^ (row & 7)) * 8);
    }
  }

  const int sc = tid & 7, sr = tid >> 3;
  const int swc = (sc ^ (sr & 7)) * 8;
  const short* WbS = (const short*)Wb;
  const short* uS = (const short*)u0;

  uint4 ra0, ra1, rb0, rb1;
  auto LOADS = [&](int s2) {
    int k = s2 >> 3, ci0 = (s2 & 7) << 6;
    const short* WbK = WbS + k * 262144 + (co0 + sr) * 512 + ci0 + sc * 8;
    const short* uK = uS + (t0 + sr + k - 1) * 512 + ci0 + sc * 8;
    ra0 = *(const uint4*)(WbK);
    ra1 = *(const uint4*)(WbK + 32 * 512);
    rb0 = *(const uint4*)(uK);
    rb1 = *(const uint4*)(uK + 32 * 512);
  };
  auto WRITE = [&](int buf) {
    *(uint4*)&As[buf][sr * 64 + swc] = ra0;
    *(uint4*)&As[buf][(sr + 32) * 64 + swc] = ra1;
    *(uint4*)&Bs[buf][sr * 64 + swc] = rb0;
    *(uint4*)&Bs[buf][(sr + 32) * 64 + swc] = rb1;
  };
  auto MFMA = [&](int buf) {
#pragma unroll
    for (int kk = 0; kk < 2; ++kk) {
      short8 av0 = *(const short8*)&As[buf][aoff[kk][0]];
      short8 av1 = *(const short8*)&As[buf][aoff[kk][1]];
      short8 bv0 = *(const short8*)&Bs[buf][boff[kk][0]];
      short8 bv1 = *(const short8*)&Bs[buf][boff[kk][1]];
      acc[0][0] = __builtin_amdgcn_mfma_f32_16x16x32_bf16(av0, bv0, acc[0][0], 0, 0, 0);
      acc[0][1] = __builtin_amdgcn_mfma_f32_16x16x32_bf16(av0, bv1, acc[0][1], 0, 0, 0);
      acc[1][0] = __builtin_amdgcn_mfma_f32_16x16x32_bf16(av1, bv0, acc[1][0], 0, 0, 0);
      acc[1][1] = __builtin_amdgcn_mfma_f32_16x16x32_bf16(av1, bv1, acc[1][1], 0, 0, 0);
    }
  };

  LOADS(0);
  WRITE(0);
  __syncthreads();
  for (int s = 0; s < 23; ++s) {
    LOADS(s + 1);              // prefetch next step (latency under MFMAs)
    MFMA(s & 1);
    WRITE((s + 1) & 1);        // other buffer: last read was at step s-1
    __syncthreads();           // ONE barrier per step
  }
  MFMA(23 & 1);

#pragma unroll
  for (int i = 0; i < 2; ++i)
#pragma unroll
    for (int r = 0; r < 4; ++r) {
      float x = fmaxf(acc[i][0][r], acc[i][1][r]);
#pragma unroll
      for (int off = 1; off < 16; off <<= 1)
        x = fmaxf(x, __shfl_xor(x, off, 64));
      if (m == 0) sm[wave][i * 16 + q * 4 + r] = x;
    }
  __syncthreads();
  if (tid < 64) {
    int whalf = tid >> 5;
    float v = fmaxf(sm[whalf * 2 + 0][tid & 31], sm[whalf * 2 + 1][tid & 31]);
    partial[(co0 + tid) * 64 + blockIdx.x] = v;
  }
}

// K5: fc1 + fc2 fused (R4-verbatim). grid 128 x 512 threads; single
// last-block agent release/acquire (count=1, cheap).
__global__ __launch_bounds__(512) void fc12_kernel(
    const float* __restrict__ partial, const float* __restrict__ bs,
    const float* __restrict__ w1, const float* __restrict__ b1,
    const float* __restrict__ w2, const float* __restrict__ b2,
    float* __restrict__ h, int* __restrict__ ctr, float* __restrict__ out) {
  __shared__ float s_r[512];
  __shared__ int s_last;
  int tid = threadIdx.x;
  {
    const float4* p = (const float4*)(partial + tid * 64);
    float mm = -INFINITY;
#pragma unroll
    for (int j = 0; j < 16; ++j) {
      float4 v = p[j];
      mm = fmaxf(mm, fmaxf(fmaxf(v.x, v.y), fmaxf(v.z, v.w)));
    }
    s_r[tid] = mm + bs[tid];
  }
  __syncthreads();
  int wave = tid >> 6, lane = tid & 63;
  int o = blockIdx.x * 8 + wave;
  const float4* wv = (const float4*)(w1 + o * 512 + lane * 8);
  const float4* rv = (const float4*)(s_r + lane * 8);
  float4 w0 = wv[0], w1v = wv[1];
  float4 r0 = rv[0], r1 = rv[1];
  float acc = w0.x * r0.x + w0.y * r0.y + w0.z * r0.z + w0.w * r0.w +
              w1v.x * r1.x + w1v.y * r1.y + w1v.z * r1.z + w1v.w * r1.w;
#pragma unroll
  for (int off = 32; off >= 1; off >>= 1) acc += __shfl_down(acc, off, 64);
  if (lane == 0) h[o] = tanhf(acc + b1[o]);
  __syncthreads();
  if (tid == 0) {
    int old = __hip_atomic_fetch_add(ctr, 1, __ATOMIC_RELEASE,
                                     __HIP_MEMORY_SCOPE_AGENT);
    s_last = (old == 127) ? 1 : 0;
  }
  __syncthreads();
  if (s_last) {
    __builtin_amdgcn_fence(__ATOMIC_ACQUIRE, "agent");
    if (tid < 128) {
      int o2 = tid >> 6;
      int lane2 = tid & 63;
      float acc2 = 0.f;
#pragma unroll
      for (int j = 0; j < 16; ++j)
        acc2 = fmaf(w2[o2 * 1024 + lane2 + j * 64], h[lane2 + j * 64], acc2);
#pragma unroll
      for (int off = 32; off >= 1; off >>= 1) acc2 += __shfl_down(acc2, off, 64);
      if (lane2 == 0) out[o2] = acc2 + b2[o2];
    }
  }
}

extern "C" void kernel_launch(void* const* d_in, const int* in_sizes, int n_in,
                              void* d_out, int out_size, void* d_ws, size_t ws_size,
                              hipStream_t stream) {
  const int*   words       = (const int*)d_in[0];
  const int*   wic         = (const int*)d_in[1];
  const float* word_emb    = (const float*)d_in[2];
  const float* chr_emb     = (const float*)d_in[3];
  const float* conv_chr_w  = (const float*)d_in[4];
  const float* conv_chr_b  = (const float*)d_in[5];
  const float* conv_sent_w = (const float*)d_in[6];
  const float* conv_sent_b = (const float*)d_in[7];
  const float* w1          = (const float*)d_in[8];
  const float* b1          = (const float*)d_in[9];
  const float* w2          = (const float*)d_in[10];
  const float* b2          = (const float*)d_in[11];
  float* out = (float*)d_out;

  float* ws    = (float*)d_ws;
  float* wT    = ws;                        // 196608 f
  float* part  = wT + 196608;               // 32768 f
  float* h_buf = part + 32768;              // 1024 f
  int*   ctr   = (int*)(h_buf + 1024);      // 4 ints
  short* Tb    = (short*)(ctr + 4);         // 98304 bf16
  short* u_base = Tb + 98304;               // 4098*512 bf16
  __hip_bfloat16* u0 = (__hip_bfloat16*)(u_base + 512);
  __hip_bfloat16* Wb = (__hip_bfloat16*)(u_base + 4098 * 512);

  prep_kernel<<<3841, 256, 0, stream>>>(conv_sent_w, conv_chr_w, wT, Wb,
                                        u_base, ctr);
  table_kernel<<<96, 256, 0, stream>>>(chr_emb, wT, (__hip_bfloat16*)Tb);
  char_word_kernel<<<512, 256, 0, stream>>>(words, wic, (const __hip_bfloat16*)Tb,
                                            word_emb, conv_chr_b, u0);
  sent_conv_mfma<<<dim3(64, 8), 256, 0, stream>>>(u0, Wb, part);
  fc12_kernel<<<128, 512, 0, stream>>>(part, conv_sent_b, w1, b1, w2, b2,
                                       h_buf, ctr, out);
}